// Round 6
// baseline (310.848 us; speedup 1.0000x reference)
//
#include <hip/hip_runtime.h>
#include <math.h>

// ---- problem constants (match reference) ----
#define N_NODES 50000
#define N_EDGES 800000
#define IN_DIM  128
#define HEADS   4
#define OUT_DIM 16
#define HD      64          // HEADS*OUT_DIM
#define NEG_SLOPE 0.2f
#define CAP     128         // per-node LDS score cache (deg > CAP -> slow path)
#define LOG2E   1.44269504088896340736f

// hardware 2^x (v_exp_f32); avoids glibc __exp2f name collision
__device__ __forceinline__ float hw_exp2(float x) {
    return __builtin_amdgcn_exp2f(x);
}

// ---------------------------------------------------------------------------
// K0: zero the per-node edge counters
// ---------------------------------------------------------------------------
__global__ void k0_zero(int* __restrict__ count) {
    int i = blockIdx.x * blockDim.x + threadIdx.x;
    if (i < N_NODES) count[i] = 0;
}

// ---------------------------------------------------------------------------
// K1: node projections + fused dst histogram.
// grid = 3125 blocks x 256 threads: 16 nodes/block AND 256 edges/block (hist).
// 4 nodes per wave; k-loop unrolled by 4 with float4 LDS reads.
// ---------------------------------------------------------------------------
__global__ __launch_bounds__(256)
void k1_proj(const float* __restrict__ x,
             const float* __restrict__ Wl, const float* __restrict__ bl,
             const float* __restrict__ Wr, const float* __restrict__ br,
             const float* __restrict__ Wres, const float* __restrict__ bres,
             const int* __restrict__ dst, int* __restrict__ count,
             float* __restrict__ xl, float* __restrict__ xr,
             float* __restrict__ xres) {
    __shared__ float xs[16][IN_DIM];
    const int base = blockIdx.x * 16;

    // fused histogram: one edge per thread (3125*256 == N_EDGES exactly)
    atomicAdd(&count[dst[blockIdx.x * 256 + threadIdx.x]], 1);

    {
        const float4* s4 = (const float4*)(x + (size_t)base * IN_DIM);
        float4* d4 = (float4*)&xs[0][0];
        for (int i = threadIdx.x; i < 16 * IN_DIM / 4; i += 256) d4[i] = s4[i];
    }
    __syncthreads();

    const int group = threadIdx.x >> 6;   // wave id: nodes base+group*4 ..+3
    const int col   = threadIdx.x & 63;

    float al[4] = {0, 0, 0, 0}, ar[4] = {0, 0, 0, 0}, as[4] = {0, 0, 0, 0};
    for (int k0 = 0; k0 < IN_DIM; k0 += 4) {
        float xv[4][4];
        *(float4*)xv[0] = *(const float4*)&xs[group * 4 + 0][k0];
        *(float4*)xv[1] = *(const float4*)&xs[group * 4 + 1][k0];
        *(float4*)xv[2] = *(const float4*)&xs[group * 4 + 2][k0];
        *(float4*)xv[3] = *(const float4*)&xs[group * 4 + 3][k0];
#pragma unroll
        for (int kk = 0; kk < 4; ++kk) {
            const float wl = Wl[(k0 + kk) * HD + col];
            const float wr = Wr[(k0 + kk) * HD + col];
            const float ws = Wres[(k0 + kk) * HD + col];
#pragma unroll
            for (int i = 0; i < 4; ++i) {
                al[i] += xv[i][kk] * wl;
                ar[i] += xv[i][kk] * wr;
                as[i] += xv[i][kk] * ws;
            }
        }
    }
    const float blv = bl[col], brv = br[col], bsv = bres[col];
    const size_t n0 = (size_t)(base + group * 4) * HD + col;
#pragma unroll
    for (int i = 0; i < 4; ++i) {
        xl[n0 + i * HD]   = al[i] + blv;
        xr[n0 + i * HD]   = ar[i] + brv;
        xres[n0 + i * HD] = as[i] + bsv;
    }
}

// ---------------------------------------------------------------------------
// K3a/b/c: two-level exclusive scan of count -> rowptr (and cursor copy)
// ---------------------------------------------------------------------------
#define SCAN_BLOCKS 196   // ceil(50000/256)

__global__ __launch_bounds__(256)
void k3a_scan1(const int* __restrict__ count, int* __restrict__ incl,
               int* __restrict__ bsum) {
    __shared__ int s[256];
    const int t = threadIdx.x;
    const int i = blockIdx.x * 256 + t;
    int c = (i < N_NODES) ? count[i] : 0;
    s[t] = c;
    __syncthreads();
    for (int off = 1; off < 256; off <<= 1) {
        int v = (t >= off) ? s[t - off] : 0;
        __syncthreads();
        s[t] += v;
        __syncthreads();
    }
    if (i < N_NODES) incl[i] = s[t];
    if (t == 255) bsum[blockIdx.x] = s[255];
}

__global__ __launch_bounds__(256)
void k3b_scan2(int* __restrict__ bsum, int* __restrict__ boff) {
    __shared__ int s[256];
    const int t = threadIdx.x;
    int c = (t < SCAN_BLOCKS) ? bsum[t] : 0;
    s[t] = c;
    __syncthreads();
    for (int off = 1; off < 256; off <<= 1) {
        int v = (t >= off) ? s[t - off] : 0;
        __syncthreads();
        s[t] += v;
        __syncthreads();
    }
    if (t < SCAN_BLOCKS) boff[t] = s[t] - c;   // exclusive
}

__global__ __launch_bounds__(256)
void k3c_scan3(const int* __restrict__ count, int* __restrict__ incl /*->rowptr*/,
               const int* __restrict__ boff, int* __restrict__ cursor) {
    const int i = blockIdx.x * 256 + threadIdx.x;
    if (i >= N_NODES) return;
    const int v = incl[i] - count[i] + boff[blockIdx.x];  // exclusive prefix
    incl[i] = v;       // rowptr
    cursor[i] = v;
}

// ---------------------------------------------------------------------------
// K4: scatter packed edge records (eid, src, ea) into CSR order — ONE 16B
//     scattered write per edge. Also emits edge_index output (float).
// ---------------------------------------------------------------------------
__global__ __launch_bounds__(256)
void k4_scatter(const int* __restrict__ src, const int* __restrict__ dst,
                const float* __restrict__ ea,
                int* __restrict__ cursor, int4* __restrict__ recs,
                float* __restrict__ out_ei) {
    int e = blockIdx.x * blockDim.x + threadIdx.x;
    if (e >= N_EDGES) return;
    const int d = dst[e];
    const int s = src[e];
    const int pos = atomicAdd(&cursor[d], 1);
    recs[pos] = make_int4(e, s, __float_as_int(ea[e]), 0);
    out_ei[e] = (float)s;
    out_ei[N_EDGES + e] = (float)d;
}

// ---------------------------------------------------------------------------
// K5: fused per-node GATv2. One wave per node; 4 edges in flight
//     (4 groups x 16 lanes; lane u owns hd = 4u..4u+3 as float4).
//     One-exp online softmax (exp2-folded), groups flash-merge via shfl_xor.
// ---------------------------------------------------------------------------
__global__ __launch_bounds__(256)
void k5_node(const int4* __restrict__ recs,
             const int* __restrict__ rowptr, const int* __restrict__ count,
             const float* __restrict__ xl, const float* __restrict__ xr,
             const float* __restrict__ xres,
             const float* __restrict__ We, const float* __restrict__ att,
             const float* __restrict__ bias_out,
             float* __restrict__ out, float* __restrict__ out_alpha) {
    __shared__ float sc_lds[4][CAP][HEADS];   // 8 KB  (scores pre-scaled by log2e)

    const int wv   = threadIdx.x >> 6;
    const int lane = threadIdx.x & 63;
    const int u    = lane & 15;           // position in group (hd = 4u..4u+3)
    const int g    = lane >> 4;           // edge group 0..3
    const int n    = blockIdx.x * 4 + wv; // grid exact: 12500*4 = 50000

    const int base = rowptr[n];
    const int deg  = count[n];

    const float4 xr4 = *(const float4*)(xr  + (size_t)n * HD + 4 * u);
    const float4 We4 = *(const float4*)(We  + 4 * u);
    float4 at4       = *(const float4*)(att + 4 * u);
    at4.x *= LOG2E; at4.y *= LOG2E; at4.z *= LOG2E; at4.w *= LOG2E;

    float m = -INFINITY, dsum = 0.f;
    float4 acc = make_float4(0.f, 0.f, 0.f, 0.f);

    for (int c0 = 0; c0 < deg; c0 += 64) {
        const int nrem = min(64, deg - c0);
        int s_my = 0; float a_my = 0.f;
        if (lane < nrem) {
            const int4 r = recs[base + c0 + lane];   // coalesced 16B
            s_my = r.y;
            a_my = __int_as_float(r.z);
        }
        const int nchunk = (nrem + 3) >> 2;

        // prefetch chunk 0 for this group
        int   j   = g;
        bool  v   = j < nrem;
        int   s   = __shfl(s_my, j);
        float aev = __shfl(a_my, j);
        float4 xlv = make_float4(0.f, 0.f, 0.f, 0.f);
        if (v) xlv = *(const float4*)(xl + (size_t)s * HD + 4 * u);

        for (int c = 0; c < nchunk; ++c) {
            const float4 cur  = xlv;
            const bool   curv = v;
            const float  ca   = aev;
            const int    cj   = 4 * c + g;
            // prefetch next chunk
            j = 4 * (c + 1) + g;
            v = j < nrem;
            s   = __shfl(s_my, j & 63);
            aev = __shfl(a_my, j & 63);
            if (v) xlv = *(const float4*)(xl + (size_t)s * HD + 4 * u);

            if (curv) {
                float f0 = cur.x + xr4.x + ca * We4.x;
                float f1 = cur.y + xr4.y + ca * We4.y;
                float f2 = cur.z + xr4.z + ca * We4.z;
                float f3 = cur.w + xr4.w + ca * We4.w;
                f0 = f0 > 0.f ? f0 : NEG_SLOPE * f0;
                f1 = f1 > 0.f ? f1 : NEG_SLOPE * f1;
                f2 = f2 > 0.f ? f2 : NEG_SLOPE * f2;
                f3 = f3 > 0.f ? f3 : NEG_SLOPE * f3;
                float p = f0 * at4.x + f1 * at4.y + f2 * at4.z + f3 * at4.w;
                p += __shfl_xor(p, 1);
                p += __shfl_xor(p, 2);     // per-head log2-scaled score
                const int jj = c0 + cj;
                if (jj < CAP && (u & 3) == 0) sc_lds[wv][jj][u >> 2] = p;
                // one-exp online update: t = 2^(-|p-m|)
                const float t    = hw_exp2(-fabsf(p - m));   // m=-inf -> 0
                const bool  up   = (p >= m);
                const float scl  = up ? t : 1.f;
                const float pe   = up ? 1.f : t;
                m = fmaxf(m, p);
                dsum  = dsum * scl + pe;
                acc.x = acc.x * scl + pe * cur.x;
                acc.y = acc.y * scl + pe * cur.y;
                acc.z = acc.z * scl + pe * cur.z;
                acc.w = acc.w * scl + pe * cur.w;
            }
        }
    }

    // flash-merge the 4 groups (lanes u, u+16, u+32, u+48 share an hd slice)
#pragma unroll
    for (int off = 16; off <= 32; off <<= 1) {
        const float mo = __shfl_xor(m, off);
        const float d2 = __shfl_xor(dsum, off);
        float4 a2;
        a2.x = __shfl_xor(acc.x, off);
        a2.y = __shfl_xor(acc.y, off);
        a2.z = __shfl_xor(acc.z, off);
        a2.w = __shfl_xor(acc.w, off);
        const float mm = fmaxf(m, mo);
        const float s1 = (m  == -INFINITY) ? 0.f : hw_exp2(m - mm);
        const float s2 = (mo == -INFINITY) ? 0.f : hw_exp2(mo - mm);
        dsum  = dsum * s1 + d2 * s2;
        acc.x = acc.x * s1 + a2.x * s2;
        acc.y = acc.y * s1 + a2.y * s2;
        acc.z = acc.z * s1 + a2.z * s2;
        acc.w = acc.w * s1 + a2.w * s2;
        m = mm;
    }
    const float inv = 1.f / (dsum + 1e-16f);

    // broadcast per-head m / inv (head h lives at lane 4h)
    const float m0 = __shfl(m, 0),  m1 = __shfl(m, 4);
    const float m2 = __shfl(m, 8),  m3 = __shfl(m, 12);
    const float i0 = __shfl(inv, 0), i1 = __shfl(inv, 4);
    const float i2 = __shfl(inv, 8), i3 = __shfl(inv, 12);

    __syncthreads();   // sc_lds visibility (uniform; each wave touches own slice)

    // alpha write pass (original edge order via record.eid)
    for (int jj = lane; jj < deg; jj += 64) {
        const int4 r = recs[base + jj];
        const int  e = r.x;
        float s0, s1, s2, s3;
        if (jj < CAP) {
            const float4 sc4 = *(const float4*)&sc_lds[wv][jj][0];
            s0 = sc4.x; s1 = sc4.y; s2 = sc4.z; s3 = sc4.w;
        } else {
            // slow path (deg > CAP): recompute from globals (log2-scaled)
            const int   sN  = r.y;
            const float aev = __int_as_float(r.z);
            float sc[4];
            for (int h2 = 0; h2 < 4; ++h2) {
                float a2 = 0.f;
                for (int d2 = 0; d2 < 16; ++d2) {
                    const int hd2 = h2 * 16 + d2;
                    float f = xl[(size_t)sN * HD + hd2] + xr[(size_t)n * HD + hd2]
                              + aev * We[hd2];
                    f = f > 0.f ? f : NEG_SLOPE * f;
                    a2 += f * att[hd2];
                }
                sc[h2] = a2 * LOG2E;
            }
            s0 = sc[0]; s1 = sc[1]; s2 = sc[2]; s3 = sc[3];
        }
        float4 a4;
        a4.x = hw_exp2(s0 - m0) * i0;
        a4.y = hw_exp2(s1 - m1) * i1;
        a4.z = hw_exp2(s2 - m2) * i2;
        a4.w = hw_exp2(s3 - m3) * i3;
        *(float4*)(out_alpha + (size_t)e * HEADS) = a4;
    }

    // final output (merged acc identical in all groups; group 0 writes)
    if (g == 0) {
        const float4 xs4 = *(const float4*)(xres + (size_t)n * HD + 4 * u);
        const float4 b4  = *(const float4*)(bias_out + 4 * u);
        float4 o;
        o.x = acc.x * inv + b4.x + xs4.x;
        o.y = acc.y * inv + b4.y + xs4.y;
        o.z = acc.z * inv + b4.z + xs4.z;
        o.w = acc.w * inv + b4.w + xs4.w;
        o.x = o.x > 0.f ? o.x : __expf(o.x) - 1.f;
        o.y = o.y > 0.f ? o.y : __expf(o.y) - 1.f;
        o.z = o.z > 0.f ? o.z : __expf(o.z) - 1.f;
        o.w = o.w > 0.f ? o.w : __expf(o.w) - 1.f;
        *(float4*)(out + (size_t)n * HD + 4 * u) = o;
    }
}

// ---------------------------------------------------------------------------
extern "C" void kernel_launch(void* const* d_in, const int* in_sizes, int n_in,
                              void* d_out, int out_size, void* d_ws, size_t ws_size,
                              hipStream_t stream) {
    const float* x        = (const float*)d_in[0];
    const int*   ei       = (const int*)d_in[1];
    const float* ea       = (const float*)d_in[2];
    const float* Wl       = (const float*)d_in[3];
    const float* bl       = (const float*)d_in[4];
    const float* Wr       = (const float*)d_in[5];
    const float* br       = (const float*)d_in[6];
    const float* We       = (const float*)d_in[7];
    const float* att      = (const float*)d_in[8];
    const float* bias_out = (const float*)d_in[9];
    const float* Wres     = (const float*)d_in[10];
    const float* bres     = (const float*)d_in[11];

    const int* src = ei;
    const int* dst = ei + N_EDGES;

    // output layout (tuple concat, float32): out | edge_index | alpha
    float* out       = (float*)d_out;
    float* out_ei    = out + (size_t)N_NODES * HD;
    float* out_alpha = out_ei + 2 * (size_t)N_EDGES;

    // workspace layout
    float* ws   = (float*)d_ws;
    float* xl   = ws;                               // N*HD
    float* xr   = xl + (size_t)N_NODES * HD;        // N*HD
    float* xres = xr + (size_t)N_NODES * HD;        // N*HD
    int* ibuf   = (int*)(xres + (size_t)N_NODES * HD);
    int* count  = ibuf;                             // N
    int* rowptr = count + N_NODES;                  // N
    int* cursor = rowptr + N_NODES;                 // N
    int* bsum   = cursor + N_NODES;                 // SCAN_BLOCKS
    int* boff   = bsum + SCAN_BLOCKS;               // SCAN_BLOCKS
    // 16B-align the record array
    size_t recoff = (size_t)(boff + SCAN_BLOCKS - (int*)d_ws);
    recoff = (recoff + 3) & ~(size_t)3;
    int4* recs  = (int4*)((int*)d_ws + recoff);     // E records (16B each)

    k0_zero<<<SCAN_BLOCKS, 256, 0, stream>>>(count);
    k1_proj<<<N_NODES / 16, 256, 0, stream>>>(x, Wl, bl, Wr, br, Wres, bres,
                                              dst, count, xl, xr, xres);
    k3a_scan1<<<SCAN_BLOCKS, 256, 0, stream>>>(count, rowptr, bsum);
    k3b_scan2<<<1, 256, 0, stream>>>(bsum, boff);
    k3c_scan3<<<SCAN_BLOCKS, 256, 0, stream>>>(count, rowptr, boff, cursor);
    k4_scatter<<<(N_EDGES + 255) / 256, 256, 0, stream>>>(src, dst, ea, cursor,
                                                          recs, out_ei);
    k5_node<<<N_NODES / 4, 256, 0, stream>>>(recs, rowptr, count,
                                             xl, xr, xres, We, att, bias_out,
                                             out, out_alpha);
}